// Round 10
// baseline (293.205 us; speedup 1.0000x reference)
//
#include <hip/hip_runtime.h>
#include <hip/hip_bf16.h>
#include <math.h>

#define Bsz  16
#define CIN  64
#define LEN  1024
#define HIDN 1024
#define OUTN 512
#define MTOT (Bsz*LEN)   // 16384
#define KTOT (3*HIDN)    // 3072 (W2T plane stride basis)
#define KT1H (2*HIDN)    // 2048 (W1T: [C2 | C3])
#define LCHUNKS 32
#define LROWS   (LEN/LCHUNKS)  // 32 rows per block

typedef __attribute__((ext_vector_type(8))) short bf16x8;
typedef __attribute__((ext_vector_type(16))) float f32x16;

__device__ __forceinline__ unsigned short f2bf(float x) {
    union { float f; unsigned int u; } v; v.f = x;
    unsigned int r = v.u + 0x7fff + ((v.u >> 16) & 1);   // RNE
    return (unsigned short)(r >> 16);
}
__device__ __forceinline__ float bf2f(unsigned short u) {
    union { unsigned int u; float f; } v; v.u = ((unsigned int)u) << 16;
    return v.f;
}
__device__ __forceinline__ void gload_lds16(const void* g, void* l) {
    __builtin_amdgcn_global_load_lds((const __attribute__((address_space(1))) void*)g,
                                     (__attribute__((address_space(3))) void*)l, 16, 0, 0);
}
// a (bf16x8) -> a2=a^2, a3=a^3 via packed RNE converts
__device__ __forceinline__ void powfrags(const bf16x8& a, bf16x8& a2, bf16x8& a3) {
#pragma unroll
    for (int j = 0; j < 4; j++) {
        float f0 = bf2f((unsigned short)a[2 * j]);
        float f1 = bf2f((unsigned short)a[2 * j + 1]);
        float s0 = f0 * f0, s1 = f1 * f1;
        __hip_bfloat162 p2 = __float22bfloat162_rn(float2{ s0, s1 });
        __hip_bfloat162 p3 = __float22bfloat162_rn(float2{ s0 * f0, s1 * f1 });
        ((unsigned int*)&a2)[j] = *(unsigned int*)&p2;
        ((unsigned int*)&a3)[j] = *(unsigned int*)&p3;
    }
}

// ---------------- prep_all: (unchanged from r9)
__global__ __launch_bounds__(256) void prep_all(const float* __restrict__ coeffs1,
                                                const float* __restrict__ bias1,
                                                const float* __restrict__ coeffs2,
                                                const float* __restrict__ bias2,
                                                const float* __restrict__ x,
                                                const float* __restrict__ Win,
                                                unsigned short* __restrict__ W1T,
                                                float* __restrict__ b1e,
                                                unsigned short* __restrict__ W2T,
                                                float* __restrict__ b2e,
                                                unsigned short* __restrict__ xT,
                                                unsigned short* __restrict__ WinT) {
    __shared__ float sm[64 * 65];
    int bid = blockIdx.x, t = threadIdx.x;
    if (bid < 1024) {
        int o = bid;
        float s = 0.f;
        unsigned short* wrow = W1T + (size_t)o * KT1H;
        for (int c = t; c < HIDN; c += 256) {
            float4 v = *(const float4*)(coeffs1 + ((size_t)o * HIDN + c) * 4);
            s += v.x;
            wrow[c]        = f2bf(v.z);
            wrow[HIDN + c] = f2bf(v.w);
        }
        for (int off = 32; off > 0; off >>= 1) s += __shfl_down(s, off, 64);
        if ((t & 63) == 0) sm[t >> 6] = s;
        __syncthreads();
        if (t == 0) b1e[o] = bias1[o] + sm[0] + sm[1] + sm[2] + sm[3];
    } else if (bid < 1536) {
        int o = bid - 1024;
        float s = 0.f;
        unsigned short* wrow = W2T + (size_t)o * KTOT;
        for (int c = t; c < HIDN; c += 256) {
            float4 v = *(const float4*)(coeffs2 + ((size_t)o * HIDN + c) * 4);
            s += v.x;
            wrow[c]            = f2bf(v.y);
            wrow[HIDN + c]     = f2bf(v.z);
            wrow[2 * HIDN + c] = f2bf(v.w);
        }
        for (int off = 32; off > 0; off >>= 1) s += __shfl_down(s, off, 64);
        if ((t & 63) == 0) sm[t >> 6] = s;
        __syncthreads();
        if (t == 0) b2e[o] = bias2[o] + sm[0] + sm[1] + sm[2] + sm[3];
    } else {
        const float* src; unsigned short* dstbase; size_t src_rstride;
        int c0;
        if (bid < 1792) {
            int tile = bid - 1536; int b = tile >> 4; c0 = (tile & 15) * 64;
            src = x + (size_t)b * CIN * LEN;  src_rstride = LEN;
            dstbase = xT + ((size_t)b * LEN + c0) * CIN;
        } else {
            int tile = bid - 1792; c0 = tile * 64;
            src = Win; src_rstride = HIDN;
            dstbase = WinT + (size_t)c0 * CIN;
        }
#pragma unroll
        for (int it = 0; it < 4; it++) {
            int idx = t + it * 256;
            int c = idx >> 4, q = idx & 15;
            float4 v = *(const float4*)(src + (size_t)c * src_rstride + c0 + q * 4);
            sm[c * 65 + q * 4 + 0] = v.x;
            sm[c * 65 + q * 4 + 1] = v.y;
            sm[c * 65 + q * 4 + 2] = v.z;
            sm[c * 65 + q * 4 + 3] = v.w;
        }
        __syncthreads();
        int ll = t >> 2, cg = (t & 3) * 16;
        unsigned short* dst = dstbase + (size_t)ll * CIN + cg;
#pragma unroll
        for (int j = 0; j < 4; j++) {
            int c = cg + j * 4;
            ushort4 w = { f2bf(sm[(c + 0) * 65 + ll]), f2bf(sm[(c + 1) * 65 + ll]),
                          f2bf(sm[(c + 2) * 65 + ll]), f2bf(sm[(c + 3) * 65 + ll]) };
            *(ushort4*)(dst + j * 4) = w;
        }
    }
}

// ---------------- wc1: WC1[o][cin] = sum_c Win[cin][c]*C1[o][c];  b1e[o] += bin . C1[o]
__global__ __launch_bounds__(256) void wc1_kernel(const float* __restrict__ coeffs1,
                                                  const unsigned short* __restrict__ WinT,
                                                  const float* __restrict__ bin,
                                                  unsigned short* __restrict__ WC1,
                                                  float* __restrict__ b1e) {
    __shared__ float c1s[HIDN];
    __shared__ float part[4][64];
    __shared__ float pbred[4];
    int o = blockIdx.x, t = threadIdx.x, lane = t & 63, wave = t >> 6;
    for (int c = t; c < HIDN; c += 256)
        c1s[c] = coeffs1[((size_t)o * HIDN + c) * 4 + 1];
    __syncthreads();
    float acc = 0.f;
    int cbase = wave * 256;
    for (int c = cbase; c < cbase + 256; c++)
        acc += bf2f(WinT[c * CIN + lane]) * c1s[c];
    part[wave][lane] = acc;
    float pb = 0.f;
    for (int c = t; c < HIDN; c += 256) pb += bin[c] * c1s[c];
    for (int off = 32; off > 0; off >>= 1) pb += __shfl_down(pb, off, 64);
    if (lane == 0) pbred[wave] = pb;
    __syncthreads();
    if (t < 64) {
        float v = part[0][t] + part[1][t] + part[2][t] + part[3][t];
        WC1[(size_t)o * CIN + t] = f2bf(v);
    }
    if (t == 0) b1e[o] += pbred[0] + pbred[1] + pbred[2] + pbred[3];
}

// ---------------- proj_mfma: h = xT @ WinT^T + bin (K=64); write ONLY h (bf16)
__global__ __launch_bounds__(256) void proj_mfma(const unsigned short* __restrict__ xT,
                                                 const unsigned short* __restrict__ WinT,
                                                 const float* __restrict__ bin,
                                                 unsigned short* __restrict__ Hout) {
    __shared__ unsigned short smem[2 * 128 * 64];
    unsigned short* As = smem;
    unsigned short* Bs = smem + 128 * 64;
    unsigned short* ht = smem;
    int t = threadIdx.x, lane = t & 63, wave = t >> 6;
    int m0 = blockIdx.x * 128, n0 = blockIdx.y * 128;
    int srow = lane >> 3, sgcc = (lane & 7) ^ srow;
    const unsigned short* Ab = xT + (size_t)m0 * CIN;
    const unsigned short* Bb = WinT + (size_t)n0 * CIN;

    f32x16 acc[2][2] = {};
    int wr = (wave >> 1) * 64, wc = (wave & 1) * 64;
    int row32 = lane & 31, half = lane >> 5;

#pragma unroll
    for (int j = 0; j < 4; j++) {
        int rgrp = wave * 32 + j * 8;
        gload_lds16(Ab + (size_t)(rgrp + srow) * CIN + sgcc * 8, As + rgrp * 64);
        gload_lds16(Bb + (size_t)(rgrp + srow) * CIN + sgcc * 8, Bs + rgrp * 64);
    }
    __syncthreads();
#pragma unroll
    for (int ks = 0; ks < 4; ks++) {
        int cidx = ks * 2 + half;
        bf16x8 af[2], bf[2];
#pragma unroll
        for (int mt = 0; mt < 2; mt++) {
            int r = wr + mt * 32 + row32;
            af[mt] = *(const bf16x8*)(As + r * 64 + ((cidx ^ (r & 7)) << 3));
        }
#pragma unroll
        for (int nt = 0; nt < 2; nt++) {
            int c = wc + nt * 32 + row32;
            bf[nt] = *(const bf16x8*)(Bs + c * 64 + ((cidx ^ (c & 7)) << 3));
        }
#pragma unroll
        for (int mt = 0; mt < 2; mt++)
#pragma unroll
            for (int nt = 0; nt < 2; nt++)
                acc[mt][nt] = __builtin_amdgcn_mfma_f32_32x32x16_bf16(af[mt], bf[nt], acc[mt][nt], 0, 0, 0);
    }
    __syncthreads();
#pragma unroll
    for (int nt = 0; nt < 2; nt++) {
        int ocl = wc + nt * 32 + row32;
        float bo = bin[n0 + ocl];
#pragma unroll
        for (int mt = 0; mt < 2; mt++) {
#pragma unroll
            for (int reg = 0; reg < 16; reg++) {
                int rl = wr + mt * 32 + (reg & 3) + 8 * (reg >> 2) + 4 * half;
                ht[rl * 128 + ocl] = f2bf(acc[mt][nt][reg] + bo);
            }
        }
    }
    __syncthreads();
#pragma unroll
    for (int p = 0; p < 8; p++) {
        int r = p * 16 + (t >> 4);
        int c = (t & 15) * 8;
        bf16x8 hv = *(const bf16x8*)(ht + r * 128 + c);
        *(bf16x8*)(Hout + (size_t)(m0 + r) * HIDN + n0 + c) = hv;
    }
}

// ---------------- kan1_gemm (BK=32, 24KB LDS): y1 = h^2@C2^T + h^3@C3^T + x@WC1^T + b1e
// Swizzle: LDS[row][slot] holds global chunk (slot ^ ((row>>1)&3)); 2-way bank alias = free.
__global__ __launch_bounds__(256) void kan1_gemm(const unsigned short* __restrict__ H,
                                                 const unsigned short* __restrict__ xT,
                                                 const unsigned short* __restrict__ W1T,
                                                 const unsigned short* __restrict__ WC1,
                                                 const float* __restrict__ beff,
                                                 unsigned short* __restrict__ Y) {
    __shared__ unsigned short smem[128 * 32 * 3];  // As 8KB + Bs 2 planes 16KB = 24KB
    unsigned short* As = smem;
    unsigned short* Bs = smem + 128 * 32;
    int t = threadIdx.x, lane = t & 63, wave = t >> 6;
    int m0 = blockIdx.x * 128, n0 = blockIdx.y * 128;
    int srow = lane >> 2;                 // 0..15
    int scc  = lane & 3;
    int sg   = scc ^ ((srow >> 1) & 3);   // global chunk fetched into our LDS slot
    const unsigned short* Ab = H + (size_t)m0 * HIDN;
    const unsigned short* Bb = W1T + (size_t)n0 * KT1H;

    f32x16 acc[2][2] = {};
    int wr = (wave >> 1) * 64, wc = (wave & 1) * 64;
    int row32 = lane & 31, half = lane >> 5;

    for (int c0 = 0; c0 < HIDN; c0 += 32) {
#pragma unroll
        for (int j = 0; j < 2; j++) {
            int rgrp = wave * 32 + j * 16;
            gload_lds16(Ab + ((size_t)(rgrp + srow) * HIDN + c0 + sg * 8), As + rgrp * 32);
#pragma unroll
            for (int p = 0; p < 2; p++)
                gload_lds16(Bb + ((size_t)(rgrp + srow) * KT1H + p * HIDN + c0 + sg * 8),
                            Bs + p * 128 * 32 + rgrp * 32);
        }
        __syncthreads();
#pragma unroll
        for (int ks = 0; ks < 2; ks++) {
            int cidx = ks * 2 + half;
            bf16x8 af2[2], af3[2];
#pragma unroll
            for (int mt = 0; mt < 2; mt++) {
                int r = wr + mt * 32 + row32;
                bf16x8 af = *(const bf16x8*)(As + r * 32 + ((cidx ^ ((r >> 1) & 3)) << 3));
                powfrags(af, af2[mt], af3[mt]);
            }
#pragma unroll
            for (int nt = 0; nt < 2; nt++) {
                int c = wc + nt * 32 + row32;
                int boff = c * 32 + ((cidx ^ ((c >> 1) & 3)) << 3);
                bf16x8 b2 = *(const bf16x8*)(Bs + boff);
                bf16x8 b3 = *(const bf16x8*)(Bs + 128 * 32 + boff);
#pragma unroll
                for (int mt = 0; mt < 2; mt++) {
                    acc[mt][nt] = __builtin_amdgcn_mfma_f32_32x32x16_bf16(af2[mt], b2, acc[mt][nt], 0, 0, 0);
                    acc[mt][nt] = __builtin_amdgcn_mfma_f32_32x32x16_bf16(af3[mt], b3, acc[mt][nt], 0, 0, 0);
                }
            }
        }
        __syncthreads();
    }
    // linear x-tail: 2 steps of K=32
    for (int c0 = 0; c0 < CIN; c0 += 32) {
#pragma unroll
        for (int j = 0; j < 2; j++) {
            int rgrp = wave * 32 + j * 16;
            gload_lds16(xT  + ((size_t)(m0 + rgrp + srow) * CIN + c0 + sg * 8), As + rgrp * 32);
            gload_lds16(WC1 + ((size_t)(n0 + rgrp + srow) * CIN + c0 + sg * 8), Bs + rgrp * 32);
        }
        __syncthreads();
#pragma unroll
        for (int ks = 0; ks < 2; ks++) {
            int cidx = ks * 2 + half;
            bf16x8 af[2], bf[2];
#pragma unroll
            for (int mt = 0; mt < 2; mt++) {
                int r = wr + mt * 32 + row32;
                af[mt] = *(const bf16x8*)(As + r * 32 + ((cidx ^ ((r >> 1) & 3)) << 3));
            }
#pragma unroll
            for (int nt = 0; nt < 2; nt++) {
                int c = wc + nt * 32 + row32;
                bf[nt] = *(const bf16x8*)(Bs + c * 32 + ((cidx ^ ((c >> 1) & 3)) << 3));
            }
#pragma unroll
            for (int mt = 0; mt < 2; mt++)
#pragma unroll
                for (int nt = 0; nt < 2; nt++)
                    acc[mt][nt] = __builtin_amdgcn_mfma_f32_32x32x16_bf16(af[mt], bf[nt], acc[mt][nt], 0, 0, 0);
        }
        __syncthreads();
    }
#pragma unroll
    for (int nt = 0; nt < 2; nt++) {
        int oc = n0 + wc + nt * 32 + row32;
        float bo = beff[oc];
#pragma unroll
        for (int mt = 0; mt < 2; mt++) {
#pragma unroll
            for (int reg = 0; reg < 16; reg++) {
                int rl = (reg & 3) + 8 * (reg >> 2) + 4 * half;
                int mr = m0 + wr + mt * 32 + rl;
                Y[(size_t)mr * HIDN + oc] = f2bf(acc[mt][nt][reg] + bo);
            }
        }
    }
}

// ---------------- LN(1024) + exact GELU, emit ONLY g (bf16); 2 rows/block
__global__ __launch_bounds__(256) void ln_gelu(const unsigned short* __restrict__ y1,
                                               const float* __restrict__ g,
                                               const float* __restrict__ be,
                                               unsigned short* __restrict__ Gonly) {
    __shared__ float2 red[2][2];
    int t = threadIdx.x;
    int rhalf = t >> 7, l = t & 127, wid = (t >> 6) & 1;
    int m = blockIdx.x * 2 + rhalf;
    bf16x8 u = *(const bf16x8*)(y1 + (size_t)m * HIDN + l * 8);
    float v[8];
    float s = 0.f, ss = 0.f;
#pragma unroll
    for (int j = 0; j < 8; j++) {
        v[j] = bf2f((unsigned short)u[j]);
        s += v[j]; ss += v[j] * v[j];
    }
    for (int off = 32; off > 0; off >>= 1) {
        s  += __shfl_down(s, off, 64);
        ss += __shfl_down(ss, off, 64);
    }
    if ((t & 63) == 0) red[rhalf][wid] = make_float2(s, ss);
    __syncthreads();
    float sT  = red[rhalf][0].x + red[rhalf][1].x;
    float ssT = red[rhalf][0].y + red[rhalf][1].y;
    float mu = sT * (1.f / HIDN);
    float var = ssT * (1.f / HIDN) - mu * mu;
    float rs = rsqrtf(var + 1e-5f);
    float4 gA = *(const float4*)(g + l * 8),  gB = *(const float4*)(g + l * 8 + 4);
    float4 bA = *(const float4*)(be + l * 8), bB = *(const float4*)(be + l * 8 + 4);
    float gv[8] = { gA.x, gA.y, gA.z, gA.w, gB.x, gB.y, gB.z, gB.w };
    float bv[8] = { bA.x, bA.y, bA.z, bA.w, bB.x, bB.y, bB.z, bB.w };
    bf16x8 p1;
#pragma unroll
    for (int j = 0; j < 8; j++) {
        float xn = (v[j] - mu) * rs * gv[j] + bv[j];
        float gl = xn * 0.5f * (1.f + erff(xn * 0.70710678118654752f));
        p1[j] = (short)f2bf(gl);
    }
    *(bf16x8*)(Gonly + (size_t)m * HIDN + l * 8) = p1;
}

// ---------------- kan2_gemm (BK=32, 32KB LDS): y2 = g@C1 + g^2@C2 + g^3@C3 + b2e
__global__ __launch_bounds__(256) void kan2_gemm(const unsigned short* __restrict__ G,
                                                 const unsigned short* __restrict__ W2T,
                                                 const float* __restrict__ beff,
                                                 unsigned short* __restrict__ Y) {
    __shared__ unsigned short smem[128 * 32 * 4];  // As 8KB + Bs 3 planes 24KB = 32KB
    unsigned short* As = smem;
    unsigned short* Bs = smem + 128 * 32;
    int t = threadIdx.x, lane = t & 63, wave = t >> 6;
    int m0 = blockIdx.x * 128, n0 = blockIdx.y * 128;
    int srow = lane >> 2;
    int scc  = lane & 3;
    int sg   = scc ^ ((srow >> 1) & 3);
    const unsigned short* Ab = G + (size_t)m0 * HIDN;
    const unsigned short* Bb = W2T + (size_t)n0 * KTOT;

    f32x16 acc[2][2] = {};
    int wr = (wave >> 1) * 64, wc = (wave & 1) * 64;
    int row32 = lane & 31, half = lane >> 5;

    for (int c0 = 0; c0 < HIDN; c0 += 32) {
#pragma unroll
        for (int j = 0; j < 2; j++) {
            int rgrp = wave * 32 + j * 16;
            gload_lds16(Ab + ((size_t)(rgrp + srow) * HIDN + c0 + sg * 8), As + rgrp * 32);
#pragma unroll
            for (int p = 0; p < 3; p++)
                gload_lds16(Bb + ((size_t)(rgrp + srow) * KTOT + p * HIDN + c0 + sg * 8),
                            Bs + p * 128 * 32 + rgrp * 32);
        }
        __syncthreads();
#pragma unroll
        for (int ks = 0; ks < 2; ks++) {
            int cidx = ks * 2 + half;
            bf16x8 af[2], af2[2], af3[2];
#pragma unroll
            for (int mt = 0; mt < 2; mt++) {
                int r = wr + mt * 32 + row32;
                af[mt] = *(const bf16x8*)(As + r * 32 + ((cidx ^ ((r >> 1) & 3)) << 3));
                powfrags(af[mt], af2[mt], af3[mt]);
            }
#pragma unroll
            for (int nt = 0; nt < 2; nt++) {
                int c = wc + nt * 32 + row32;
                int boff = c * 32 + ((cidx ^ ((c >> 1) & 3)) << 3);
                bf16x8 b1 = *(const bf16x8*)(Bs + boff);
                bf16x8 b2 = *(const bf16x8*)(Bs + 128 * 32 + boff);
                bf16x8 b3 = *(const bf16x8*)(Bs + 2 * 128 * 32 + boff);
#pragma unroll
                for (int mt = 0; mt < 2; mt++) {
                    acc[mt][nt] = __builtin_amdgcn_mfma_f32_32x32x16_bf16(af[mt],  b1, acc[mt][nt], 0, 0, 0);
                    acc[mt][nt] = __builtin_amdgcn_mfma_f32_32x32x16_bf16(af2[mt], b2, acc[mt][nt], 0, 0, 0);
                    acc[mt][nt] = __builtin_amdgcn_mfma_f32_32x32x16_bf16(af3[mt], b3, acc[mt][nt], 0, 0, 0);
                }
            }
        }
        __syncthreads();
    }
#pragma unroll
    for (int nt = 0; nt < 2; nt++) {
        int oc = n0 + wc + nt * 32 + row32;
        float bo = beff[oc];
#pragma unroll
        for (int mt = 0; mt < 2; mt++) {
#pragma unroll
            for (int reg = 0; reg < 16; reg++) {
                int rl = (reg & 3) + 8 * (reg >> 2) + 4 * half;
                int mr = m0 + wr + mt * 32 + rl;
                Y[(size_t)mr * OUTN + oc] = f2bf(acc[mt][nt][reg] + bo);
            }
        }
    }
}

// ---------------- Stage A: LN(512) per row (bf16 y2) + partial mean over L-chunk
__global__ __launch_bounds__(256) void ln_pool_partial(const unsigned short* __restrict__ y2,
                                                       const float* __restrict__ g,
                                                       const float* __restrict__ be,
                                                       float* __restrict__ partial) {
    __shared__ float part[4][OUTN];
    int t = threadIdx.x, lane = t & 63, wave = t >> 6;
    int b = blockIdx.x, chunk = blockIdx.y;
    int mbase = b * LEN + chunk * LROWS;

    float4 gA = *(const float4*)(g + 8 * lane),  gB = *(const float4*)(g + 8 * lane + 4);
    float4 bA = *(const float4*)(be + 8 * lane), bB = *(const float4*)(be + 8 * lane + 4);
    float gv[8] = { gA.x, gA.y, gA.z, gA.w, gB.x, gB.y, gB.z, gB.w };
    float bv[8] = { bA.x, bA.y, bA.z, bA.w, bB.x, bB.y, bB.z, bB.w };

    float acc[8] = {0.f, 0.f, 0.f, 0.f, 0.f, 0.f, 0.f, 0.f};
    for (int rr = wave; rr < LROWS; rr += 4) {
        bf16x8 u = *(const bf16x8*)(y2 + (size_t)(mbase + rr) * OUTN + 8 * lane);
        float v[8];
        float s = 0.f, ss = 0.f;
#pragma unroll
        for (int j = 0; j < 8; j++) {
            v[j] = bf2f((unsigned short)u[j]);
            s += v[j]; ss += v[j] * v[j];
        }
        for (int off = 32; off > 0; off >>= 1) {
            s  += __shfl_down(s, off, 64);
            ss += __shfl_down(ss, off, 64);
        }
        s  = __shfl(s, 0, 64);
        ss = __shfl(ss, 0, 64);
        float mu = s * (1.f / OUTN);
        float var = ss * (1.f / OUTN) - mu * mu;
        float rs = rsqrtf(var + 1e-5f);
#pragma unroll
        for (int j = 0; j < 8; j++)
            acc[j] += (v[j] - mu) * rs * gv[j] + bv[j];
    }
    *(float4*)(&part[wave][8 * lane])     = *(float4*)(&acc[0]);
    *(float4*)(&part[wave][8 * lane + 4]) = *(float4*)(&acc[4]);
    __syncthreads();
    float p0 = part[0][2*t] + part[1][2*t] + part[2][2*t] + part[3][2*t];
    float p1 = part[0][2*t+1] + part[1][2*t+1] + part[2][2*t+1] + part[3][2*t+1];
    float* dst = partial + ((size_t)b * LCHUNKS + chunk) * OUTN;
    *(float2*)(dst + 2 * t) = make_float2(p0, p1);
}

// ---------------- Stage B: reduce 32 chunk-partials -> out[b][o]
__global__ __launch_bounds__(256) void pool_reduce(const float* __restrict__ partial,
                                                   float* __restrict__ out) {
    int b = blockIdx.x, t = threadIdx.x;
    const float* src = partial + (size_t)b * LCHUNKS * OUTN;
    float s0 = 0.f, s1 = 0.f;
    for (int c = 0; c < LCHUNKS; c++) {
        float2 v = *(const float2*)(src + (size_t)c * OUTN + 2 * t);
        s0 += v.x; s1 += v.y;
    }
    *(float2*)(out + (size_t)b * OUTN + 2 * t) = make_float2(s0 * (1.f / LEN), s1 * (1.f / LEN));
}

extern "C" void kernel_launch(void* const* d_in, const int* in_sizes, int n_in,
                              void* d_out, int out_size, void* d_ws, size_t ws_size,
                              hipStream_t stream) {
    const float* x       = (const float*)d_in[0];
    const float* Win     = (const float*)d_in[1];
    const float* bin     = (const float*)d_in[2];
    const float* coeffs1 = (const float*)d_in[3];
    const float* bias1   = (const float*)d_in[4];
    const float* g1      = (const float*)d_in[5];
    const float* beta1   = (const float*)d_in[6];
    const float* coeffs2 = (const float*)d_in[7];
    const float* bias2   = (const float*)d_in[8];
    const float* g2      = (const float*)d_in[9];
    const float* beta2   = (const float*)d_in[10];
    float* out = (float*)d_out;

    char* ws = (char*)d_ws;
    unsigned short* Hpln  = (unsigned short*)ws;
    unsigned short* Gonly = (unsigned short*)ws;                        // 33,554,432 B
    char* p1 = ws + (size_t)MTOT * HIDN * 2;
    unsigned short* y1   = (unsigned short*)p1;                         // 33,554,432 B
    unsigned short* y2   = (unsigned short*)p1;                         // alias (16 MB)
    char* p2 = p1 + (size_t)MTOT * HIDN * 2;
    unsigned short* W1T  = (unsigned short*)p2;                         // 4 MB
    char* p3 = p2 + (size_t)HIDN * KT1H * 2;
    unsigned short* W2T  = (unsigned short*)p3;                         // 3 MB
    char* p4 = p3 + (size_t)OUTN * KTOT * 2;
    float* b1e = (float*)p4;
    float* b2e = (float*)(p4 + HIDN * sizeof(float));
    char* p5 = p4 + (HIDN + OUTN) * sizeof(float);
    unsigned short* xT   = (unsigned short*)p5;                         // 2 MB
    char* p6 = p5 + (size_t)MTOT * CIN * 2;
    unsigned short* WinT = (unsigned short*)p6;                         // 128 KB
    char* p7 = p6 + (size_t)HIDN * CIN * 2;
    unsigned short* WC1  = (unsigned short*)p7;                         // 128 KB
    float* partial = (float*)W1T;    // alias: W1T dead after kan1_gemm

    prep_all<<<1808, 256, 0, stream>>>(coeffs1, bias1, coeffs2, bias2, x, Win,
                                       W1T, b1e, W2T, b2e, xT, WinT);
    wc1_kernel<<<HIDN, 256, 0, stream>>>(coeffs1, WinT, bin, WC1, b1e);
    proj_mfma<<<dim3(MTOT / 128, HIDN / 128), 256, 0, stream>>>(xT, WinT, bin, Hpln);
    kan1_gemm<<<dim3(MTOT / 128, HIDN / 128), 256, 0, stream>>>(Hpln, xT, W1T, WC1, b1e, y1);
    ln_gelu<<<MTOT / 2, 256, 0, stream>>>(y1, g1, beta1, Gonly);
    kan2_gemm<<<dim3(MTOT / 128, OUTN / 128), 256, 0, stream>>>(Gonly, W2T, b2e, y2);
    ln_pool_partial<<<dim3(Bsz, LCHUNKS), 256, 0, stream>>>(y2, g2, beta2, partial);
    pool_reduce<<<Bsz, 256, 0, stream>>>(partial, out);
}